// Round 4
// baseline (137.992 us; speedup 1.0000x reference)
//
#include <hip/hip_runtime.h>

#define NB  32
#define NLQ 64
#define NLV 128
#define NQS 512
#define NFS 1024
#define NBN 512
#define CC  2.8853900817779268f   // 2*log2(e):  exp(2x) = exp2(CC*x)

typedef float  floatx4 __attribute__((ext_vector_type(4)));
typedef __bf16 bf16x8  __attribute__((ext_vector_type(8)));
typedef unsigned short us;

__device__ __forceinline__ us f2bf(float f) {
    unsigned int u = __float_as_uint(f);
    u += 0x7fffu + ((u >> 16) & 1u);   // round-to-nearest-even
    return (us)(u >> 16);
}
// truncating pack of two fp32 -> packed bf16x2, one v_perm_b32
__device__ __forceinline__ unsigned int pktrunc(float lo, float hi) {
    return __builtin_amdgcn_perm(__float_as_uint(hi), __float_as_uint(lo), 0x07060302u);
}
__device__ __forceinline__ float blo(unsigned int u) {
    return __uint_as_float(u << 16);
}
__device__ __forceinline__ float bhi(unsigned int u) {
    return __uint_as_float(u & 0xffff0000u);
}

// ---------------- GEMM: 128x128 block, K-tile 32, 4 waves, per-wave 64x64 ---
// (m93 geometry: 16 MFMA / 8 frags per wave-K-tile -> 0.75 KB LDS per MFMA)
// mode Yq (whYp != null): C = exp2(CC*(acc+bias)) stored FP32 to whY[2048][512]
//   blocks with by==0 also copy fp32 A rows into out_sgf[:, 0:512].
// mode Yv (uvYTp != null): C = exp2(CC*acc) stored bf16 TRANSPOSED to
//   uvYT[b][n][v]  (block covers exactly batch bb=bx: v = 0..127).
__device__ __forceinline__ void gemm128(
    us* As, us* Bs,                       // [128*40] each
    const float* __restrict__ A, const float* __restrict__ Bt,
    const float* __restrict__ bias,
    float* __restrict__ whYp, us* __restrict__ uvYTp,
    int K, int bx, int by, float* __restrict__ sgf)
{
    const int tid  = threadIdx.x;
    const int m0   = bx * 128;
    const int n0   = by * 128;
    const int wave = tid >> 6;
    const int lane = tid & 63;
    const int wm   = (wave >> 1) * 64;
    const int wn   = (wave & 1) * 64;
    const int srow = tid >> 1;          // 0..127
    const int sk   = (tid & 1) * 16;    // k offset (elements): 0,16
    const int fm   = lane & 15;
    const int fko  = (lane >> 4) * 8;

    floatx4 acc[4][4] = {};
    const float* ag = A  + (size_t)(m0 + srow) * K + sk;
    const float* bg = Bt + (size_t)(n0 + srow) * K + sk;

    float4 a[4], b[4];
    #pragma unroll
    for (int r = 0; r < 4; ++r) { a[r] = ((const float4*)ag)[r]; b[r] = ((const float4*)bg)[r]; }

    for (int k0 = 0; k0 < K; k0 += 32) {
        __syncthreads();
        if (sgf) {          // concat left half: fp32, exact
            float* d = sgf + (size_t)(m0 + srow) * (NQS + NFS) + k0 + sk;
            #pragma unroll
            for (int r = 0; r < 4; ++r) *(float4*)(d + 4 * r) = a[r];
        }
        uint4 av0 = { pktrunc(a[0].x, a[0].y), pktrunc(a[0].z, a[0].w),
                      pktrunc(a[1].x, a[1].y), pktrunc(a[1].z, a[1].w) };
        uint4 av1 = { pktrunc(a[2].x, a[2].y), pktrunc(a[2].z, a[2].w),
                      pktrunc(a[3].x, a[3].y), pktrunc(a[3].z, a[3].w) };
        uint4 bv0 = { pktrunc(b[0].x, b[0].y), pktrunc(b[0].z, b[0].w),
                      pktrunc(b[1].x, b[1].y), pktrunc(b[1].z, b[1].w) };
        uint4 bv1 = { pktrunc(b[2].x, b[2].y), pktrunc(b[2].z, b[2].w),
                      pktrunc(b[3].x, b[3].y), pktrunc(b[3].z, b[3].w) };
        *(uint4*)(As + srow * 40 + sk)     = av0;
        *(uint4*)(As + srow * 40 + sk + 8) = av1;
        *(uint4*)(Bs + srow * 40 + sk)     = bv0;
        *(uint4*)(Bs + srow * 40 + sk + 8) = bv1;
        const int kn = k0 + 32;
        if (kn < K) {                   // next-tile prefetch
            #pragma unroll
            for (int r = 0; r < 4; ++r) {
                a[r] = *(const float4*)(ag + kn + 4 * r);
                b[r] = *(const float4*)(bg + kn + 4 * r);
            }
        }
        __syncthreads();
        bf16x8 am[4], bn[4];
        #pragma unroll
        for (int i = 0; i < 4; ++i)
            am[i] = *(const bf16x8*)(As + (wm + 16 * i + fm) * 40 + fko);
        #pragma unroll
        for (int j = 0; j < 4; ++j)
            bn[j] = *(const bf16x8*)(Bs + (wn + 16 * j + fm) * 40 + fko);
        #pragma unroll
        for (int i = 0; i < 4; ++i)
            #pragma unroll
            for (int j = 0; j < 4; ++j)
                acc[i][j] = __builtin_amdgcn_mfma_f32_16x16x32_bf16(am[i], bn[j], acc[i][j], 0, 0, 0);
    }

    // C/D layout: col = lane&15, row = (lane>>4)*4 + reg
    const int cr = (lane >> 4) * 4;
    const int cc = lane & 15;
    if (whYp) {
        #pragma unroll
        for (int j = 0; j < 4; ++j) {
            int gn = n0 + wn + 16 * j + cc;
            float bj = bias[gn];
            #pragma unroll
            for (int i = 0; i < 4; ++i)
                #pragma unroll
                for (int r = 0; r < 4; ++r) {
                    int gm = m0 + wm + 16 * i + cr + r;
                    whYp[(size_t)gm * NBN + gn] =
                        __builtin_amdgcn_exp2f(CC * (acc[i][j][r] + bj));
                }
        }
    } else {
        const int bb = bx;                         // block spans v = 0..127
        #pragma unroll
        for (int i = 0; i < 4; ++i)
            #pragma unroll
            for (int j = 0; j < 4; ++j) {
                int v0 = wm + 16 * i + cr;         // v-run base (4 rows)
                int gn = n0 + wn + 16 * j + cc;    // n
                unsigned int y0 = f2bf(__builtin_amdgcn_exp2f(CC * acc[i][j][0]));
                unsigned int y1 = f2bf(__builtin_amdgcn_exp2f(CC * acc[i][j][1]));
                unsigned int y2 = f2bf(__builtin_amdgcn_exp2f(CC * acc[i][j][2]));
                unsigned int y3 = f2bf(__builtin_amdgcn_exp2f(CC * acc[i][j][3]));
                uint2 pk2 = { y0 | (y1 << 16), y2 | (y3 << 16) };
                *(uint2*)(uvYTp + ((size_t)bb * NBN + gn) * NLV + v0) = pk2;
            }
    }
}

// blocks 0..63: Yq (M=2048,K=512: bx 0..15, by 0..3)
// blocks 64..191: Yv (M=4096,K=1024: bx 0..31, by 0..3)
__global__ __launch_bounds__(256) void gemm_both(
    const float* __restrict__ phr, const float* __restrict__ W,
    const float* __restrict__ bias,
    const float* __restrict__ vis, const float* __restrict__ U,
    float* __restrict__ whY, us* __restrict__ uvYT,
    float* __restrict__ out_sgf)
{
    __shared__ __align__(16) us As[128 * 40];
    __shared__ __align__(16) us Bs[128 * 40];
    int blk = blockIdx.x;
    if (blk < 64) {
        int bx = blk & 15, by = blk >> 4;
        gemm128(As, Bs, phr, W, bias, whY, nullptr, NQS, bx, by,
                by == 0 ? out_sgf : nullptr);
    } else {
        blk -= 64;
        int bx = blk & 31, by = blk >> 5;
        gemm128(As, Bs, vis, U, bias, nullptr, uvYT, NFS, bx, by, nullptr);
    }
}

// ---------------- energize: in-thread n-reduction, zero shuffle-reduce ------
// block = (b, q-quad), 4 waves = n-quarters. lane owns v-pair (2*lane, 2*lane+1).
// Yq (fp32) and w are wave-uniform -> scalar loads; Yv from transposed uvYT.
__global__ __launch_bounds__(256) void energize(
    const float* __restrict__ whY,    // [2048][512] fp32 = exp(2(Wh+b))
    const us* __restrict__ uvYT,      // [32][512][128] bf16 = exp(2Uv), [n][v]
    const float* __restrict__ wvec,   // [512]
    float* __restrict__ out_w, float* __restrict__ out_e,
    us* __restrict__ p_bf, us* __restrict__ p_lo)   // [2048][128]
{
    const float LOG2E = 1.4426950408889634f;
    int blk = blockIdx.x;
    blk = (blk & 7) * 64 + (blk >> 3);    // bijective XCD swizzle (512 = 8*64)
    const int b    = blk >> 4;            // b-major: 16 blocks share uvYT[b]
    const int qq4  = blk & 15;
    const int tid  = threadIdx.x;
    const int wave = __builtin_amdgcn_readfirstlane(tid >> 6);  // n-quarter
    const int lane = tid & 63;
    const int q0   = qq4 * 4;

    __shared__ float part[4][4][NLV];     // [q][nq][v]

    // sumw (once per wave)
    float4 sw0 = *(const float4*)(wvec + lane * 8);
    float4 sw1 = *(const float4*)(wvec + lane * 8 + 4);
    float sumw = sw0.x + sw0.y + sw0.z + sw0.w + sw1.x + sw1.y + sw1.z + sw1.w;
    #pragma unroll
    for (int off = 32; off; off >>= 1) sumw += __shfl_xor(sumw, off);

    const float* yqp = whY + (size_t)(b * NLQ + q0) * NBN + wave * 128;
    const float* wp  = wvec + wave * 128;
    const us*    uvp = uvYT + ((size_t)b * NBN + wave * 128) * NLV + 2 * lane;

    float acc[4][2] = {};
    #pragma unroll 2
    for (int nc = 0; nc < 128; nc += 8) {
        unsigned int yv[8];
        #pragma unroll
        for (int k = 0; k < 8; ++k)
            yv[k] = *(const unsigned int*)(uvp + (size_t)(nc + k) * NLV);
        #pragma unroll
        for (int k = 0; k < 8; ++k) {
            float x0 = blo(yv[k]), x1 = bhi(yv[k]);
            float wk = wp[nc + k];                      // uniform -> SGPR
            #pragma unroll
            for (int q = 0; q < 4; ++q) {
                float yq = yqp[q * NBN + nc + k];       // uniform -> SGPR
                float d0 = fmaf(x0, yq, 1.f);
                float d1 = fmaf(x1, yq, 1.f);
                acc[q][0] = fmaf(wk, __builtin_amdgcn_rcpf(d0), acc[q][0]);
                acc[q][1] = fmaf(wk, __builtin_amdgcn_rcpf(d1), acc[q][1]);
            }
        }
    }
    #pragma unroll
    for (int q = 0; q < 4; ++q) {
        float2 t = { acc[q][0], acc[q][1] };
        *(float2*)&part[q][wave][2 * lane] = t;
    }
    __syncthreads();

    // softmax: wave w handles q = w (exactly 4 q, 4 waves)
    const int q = wave;
    float s0 = 0.f, s1 = 0.f;
    #pragma unroll
    for (int nq = 0; nq < 4; ++nq) {
        s0 += part[q][nq][2 * lane];
        s1 += part[q][nq][2 * lane + 1];
    }
    float e0 = sumw - 2.f * s0;
    float e1 = sumw - 2.f * s1;
    float m = fmaxf(e0, e1);
    #pragma unroll
    for (int off = 32; off; off >>= 1) m = fmaxf(m, __shfl_xor(m, off));
    float x0 = __builtin_amdgcn_exp2f((e0 - m) * LOG2E);
    float x1 = __builtin_amdgcn_exp2f((e1 - m) * LOG2E);
    float ss = x0 + x1;
    #pragma unroll
    for (int off = 32; off; off >>= 1) ss += __shfl_xor(ss, off);
    float inv = __builtin_amdgcn_rcpf(ss);
    float p0 = x0 * inv, p1 = x1 * inv;

    const size_t row = (size_t)(b * NLQ + q0 + q);
    float2 ep = { e0, e1 };
    float2 pp = { p0, p1 };
    *(float2*)(out_e + row * NLV + 2 * lane) = ep;
    *(float2*)(out_w + row * NLV + 2 * lane) = pp;
    // bf16 p + bf16 correction (restores fp32 accuracy in the MFMA)
    unsigned int pb0 = f2bf(p0), pb1 = f2bf(p1);
    float lo0 = p0 - __uint_as_float(pb0 << 16);
    float lo1 = p1 - __uint_as_float(pb1 << 16);
    unsigned int lb0 = f2bf(lo0), lb1 = f2bf(lo1);
    *(unsigned int*)(p_bf + row * NLV + 2 * lane) = pb0 | (pb1 << 16);
    *(unsigned int*)(p_lo + row * NLV + 2 * lane) = lb0 | (lb1 << 16);
}

// ---------------- aligned via MFMA: out = (P + P_lo) . V ---------------------
// block = (b, f-tile of 64). Stages its own V slice from fp32 vis:
// load coalesced, truncate to bf16, LDS-transpose to Vs[f][v] (pad 136).
// A-frags (P) gather directly from L2; B-frags from LDS.
__global__ __launch_bounds__(256) void aligned_mfma(
    const us* __restrict__ p_bf, const us* __restrict__ p_lo,  // [2048][128]
    const float* __restrict__ vis,                             // [32][128][1024]
    float* __restrict__ out_sgf)
{
    int blk = blockIdx.x;
    blk = (blk & 7) * 64 + (blk >> 3);    // XCD swizzle, b-major
    const int b    = blk >> 4;
    const int ft   = blk & 15;
    const int tid  = threadIdx.x;
    const int wave = tid >> 6;
    const int lane = tid & 63;
    const int wm   = (wave >> 1) * 32;    // q offset
    const int wf   = (wave & 1) * 32;     // f offset within the 64-tile
    const int fm   = lane & 15;
    const int fko  = (lane >> 4) * 8;

    __shared__ us Vs[64][136];            // [f][v], row stride 272 B (16B mult)

    {   // stage V: thread owns (v = tid>>1, f-half = (tid&1)*32)
        const int v  = tid >> 1;
        const int fh = (tid & 1) * 32;
        const float* vp = vis + ((size_t)b * NLV + v) * NFS + ft * 64 + fh;
        #pragma unroll
        for (int r = 0; r < 8; ++r) {
            float4 x = ((const float4*)vp)[r];
            Vs[fh + 4 * r + 0][v] = (us)(__float_as_uint(x.x) >> 16);
            Vs[fh + 4 * r + 1][v] = (us)(__float_as_uint(x.y) >> 16);
            Vs[fh + 4 * r + 2][v] = (us)(__float_as_uint(x.z) >> 16);
            Vs[fh + 4 * r + 3][v] = (us)(__float_as_uint(x.w) >> 16);
        }
    }
    __syncthreads();

    floatx4 acc[2][2] = {};
    const us* pA  = p_bf + ((size_t)b * NLQ + wm + fm) * NLV + fko;
    const us* pAl = p_lo + ((size_t)b * NLQ + wm + fm) * NLV + fko;

    #pragma unroll
    for (int ks = 0; ks < 4; ++ks) {
        bf16x8 a[2], al[2], bb2[2];
        #pragma unroll
        for (int i = 0; i < 2; ++i) {
            a[i]  = *(const bf16x8*)(pA  + (size_t)i * 16 * NLV + ks * 32);
            al[i] = *(const bf16x8*)(pAl + (size_t)i * 16 * NLV + ks * 32);
        }
        #pragma unroll
        for (int j = 0; j < 2; ++j)
            bb2[j] = *(const bf16x8*)&Vs[wf + 16 * j + fm][ks * 32 + fko];
        #pragma unroll
        for (int i = 0; i < 2; ++i)
            #pragma unroll
            for (int j = 0; j < 2; ++j) {
                acc[i][j] = __builtin_amdgcn_mfma_f32_16x16x32_bf16(a[i],  bb2[j], acc[i][j], 0, 0, 0);
                acc[i][j] = __builtin_amdgcn_mfma_f32_16x16x32_bf16(al[i], bb2[j], acc[i][j], 0, 0, 0);
            }
    }

    const int cr = (lane >> 4) * 4;
    const int cc = lane & 15;
    #pragma unroll
    for (int i = 0; i < 2; ++i)
        #pragma unroll
        for (int j = 0; j < 2; ++j)
            #pragma unroll
            for (int r = 0; r < 4; ++r) {
                int q = wm + 16 * i + cr + r;
                int f = ft * 64 + wf + 16 * j + cc;
                size_t row = (size_t)b * NLQ + q;
                out_sgf[row * (NQS + NFS) + NQS + f] = acc[i][j][r];
            }
}

extern "C" void kernel_launch(void* const* d_in, const int* in_sizes, int n_in,
                              void* d_out, int out_size, void* d_ws, size_t ws_size,
                              hipStream_t stream) {
    const float* phr  = (const float*)d_in[0];
    const float* vis  = (const float*)d_in[1];
    const float* W    = (const float*)d_in[2];
    const float* U    = (const float*)d_in[3];
    const float* bias = (const float*)d_in[4];
    const float* wvec = (const float*)d_in[5];

    char* ws = (char*)d_ws;
    float* whY  = (float*)ws;                     // 4 MB [2048][512] fp32
    us* uvYT    = (us*)(ws + (4u << 20));         // 4 MB [32][512][128] bf16
    us* p_bf    = (us*)(ws + (8u << 20));         // 512 KB [2048][128]
    us* p_lo    = (us*)(ws + (8u << 20) + (512u << 10));    // 512 KB

    float* out     = (float*)d_out;
    float* out_sgf = out;
    float* out_w   = out_sgf + (size_t)NB * NLQ * (NQS + NFS);
    float* out_e   = out_w   + (size_t)NB * NLQ * NLV;

    gemm_both<<<192, 256, 0, stream>>>(phr, W, bias, vis, U, whY, uvYT, out_sgf);
    energize<<<512, 256, 0, stream>>>(whY, uvYT, wvec, out_w, out_e, p_bf, p_lo);
    aligned_mfma<<<512, 256, 0, stream>>>(p_bf, p_lo, vis, out_sgf);
}

// Round 5
// 126.305 us; speedup vs baseline: 1.0925x; 1.0925x over previous
//
#include <hip/hip_runtime.h>

#define NB  32
#define NLQ 64
#define NLV 128
#define NQS 512
#define NFS 1024
#define NBN 512
#define CC  2.8853900817779268f   // 2*log2(e):  exp(2x) = exp2(CC*x)

typedef float  floatx4 __attribute__((ext_vector_type(4)));
typedef __bf16 bf16x8  __attribute__((ext_vector_type(8)));
typedef unsigned short us;

__device__ __forceinline__ us f2bf(float f) {
    unsigned int u = __float_as_uint(f);
    u += 0x7fffu + ((u >> 16) & 1u);   // round-to-nearest-even
    return (us)(u >> 16);
}
// truncating pack of two fp32 -> packed bf16x2, one v_perm_b32
__device__ __forceinline__ unsigned int pktrunc(float lo, float hi) {
    return __builtin_amdgcn_perm(__float_as_uint(hi), __float_as_uint(lo), 0x07060302u);
}
__device__ __forceinline__ float blo(unsigned int u) {
    return __uint_as_float(u << 16);
}
__device__ __forceinline__ float bhi(unsigned int u) {
    return __uint_as_float(u & 0xffff0000u);
}

// ---------------- GEMM: 64x64 tile, K-tile 32, fp32 in (cvt in-reg), 4 waves
// 768-block grid (~3 blocks/CU) -> inter-block overlap hides prefetch+barrier
// latency (the 128x128/192-block variant measured 45 us at 5.9% occupancy).
// mode Yq (whYp != null): C = exp2(CC*(acc+bias)) stored FP32 to whY[2048][512]
//   by==0 blocks also copy fp32 A rows into out_sgf[:, 0:512].
// mode Yv (uvYTp != null): C = exp2(CC*acc) stored bf16 TRANSPOSED to
//   uvYT[b][n][v].
__device__ __forceinline__ void gemm64(
    us* As, us* Bs,                       // [64*40] each
    const float* __restrict__ A, const float* __restrict__ Bt,
    const float* __restrict__ bias,
    float* __restrict__ whYp, us* __restrict__ uvYTp,
    int K, int bx, int by, float* __restrict__ sgf)
{
    const int tid  = threadIdx.x;
    const int m0   = bx * 64;
    const int n0   = by * 64;
    const int wave = tid >> 6;
    const int lane = tid & 63;
    const int wm   = (wave >> 1) * 32;
    const int wn   = (wave & 1) * 32;
    const int srow = tid >> 2;          // 0..63
    const int sk   = (tid & 3) * 8;     // k offset (elements): 0,8,16,24
    const int fm   = lane & 15;
    const int fko  = (lane >> 4) * 8;

    floatx4 acc[2][2] = {};
    const float* ag = A  + (size_t)(m0 + srow) * K + sk;
    const float* bg = Bt + (size_t)(n0 + srow) * K + sk;

    float4 a0 = *(const float4*)(ag),     a1 = *(const float4*)(ag + 4);
    float4 b0 = *(const float4*)(bg),     b1 = *(const float4*)(bg + 4);

    for (int k0 = 0; k0 < K; k0 += 32) {
        __syncthreads();
        if (sgf) {          // concat left half: fp32, exact
            float* d = sgf + (size_t)(m0 + srow) * (NQS + NFS) + k0 + sk;
            *(float4*)d       = a0;
            *(float4*)(d + 4) = a1;
        }
        uint4 av = { pktrunc(a0.x, a0.y), pktrunc(a0.z, a0.w),
                     pktrunc(a1.x, a1.y), pktrunc(a1.z, a1.w) };
        uint4 bv = { pktrunc(b0.x, b0.y), pktrunc(b0.z, b0.w),
                     pktrunc(b1.x, b1.y), pktrunc(b1.z, b1.w) };
        *(uint4*)(As + srow * 40 + sk) = av;
        *(uint4*)(Bs + srow * 40 + sk) = bv;
        const int kn = k0 + 32;
        if (kn < K) {                   // next-tile prefetch; hidden by co-resident blocks
            a0 = *(const float4*)(ag + kn); a1 = *(const float4*)(ag + kn + 4);
            b0 = *(const float4*)(bg + kn); b1 = *(const float4*)(bg + kn + 4);
        }
        __syncthreads();
        bf16x8 am[2], bn[2];
        #pragma unroll
        for (int i = 0; i < 2; ++i)
            am[i] = *(const bf16x8*)(As + (wm + 16 * i + fm) * 40 + fko);
        #pragma unroll
        for (int j = 0; j < 2; ++j)
            bn[j] = *(const bf16x8*)(Bs + (wn + 16 * j + fm) * 40 + fko);
        #pragma unroll
        for (int i = 0; i < 2; ++i)
            #pragma unroll
            for (int j = 0; j < 2; ++j)
                acc[i][j] = __builtin_amdgcn_mfma_f32_16x16x32_bf16(am[i], bn[j], acc[i][j], 0, 0, 0);
    }

    // C/D layout: col = lane&15, row = (lane>>4)*4 + reg
    const int cr = (lane >> 4) * 4;
    const int cc = lane & 15;
    if (whYp) {
        #pragma unroll
        for (int j = 0; j < 2; ++j) {
            int gn = n0 + wn + 16 * j + cc;
            float bj = bias[gn];
            #pragma unroll
            for (int i = 0; i < 2; ++i)
                #pragma unroll
                for (int r = 0; r < 4; ++r) {
                    int gm = m0 + wm + 16 * i + cr + r;
                    whYp[(size_t)gm * NBN + gn] =
                        __builtin_amdgcn_exp2f(CC * (acc[i][j][r] + bj));
                }
        }
    } else {
        #pragma unroll
        for (int i = 0; i < 2; ++i)
            #pragma unroll
            for (int j = 0; j < 2; ++j) {
                int gm0 = m0 + wm + 16 * i + cr;       // v-run base (4 rows)
                int gn  = n0 + wn + 16 * j + cc;       // n
                int bb  = gm0 >> 7, v0 = gm0 & 127;
                unsigned int y0 = f2bf(__builtin_amdgcn_exp2f(CC * acc[i][j][0]));
                unsigned int y1 = f2bf(__builtin_amdgcn_exp2f(CC * acc[i][j][1]));
                unsigned int y2 = f2bf(__builtin_amdgcn_exp2f(CC * acc[i][j][2]));
                unsigned int y3 = f2bf(__builtin_amdgcn_exp2f(CC * acc[i][j][3]));
                uint2 pk2 = { y0 | (y1 << 16), y2 | (y3 << 16) };
                *(uint2*)(uvYTp + ((size_t)bb * NBN + gn) * NLV + v0) = pk2;
            }
    }
}

// blocks 0..255: Yq (M=2048,K=512, nbx=32); 256..767: Yv (M=4096,K=1024, nbx=64)
// bx = blk % nbx with 8|nbx -> blocks sharing A-rows land on one XCD's L2
__global__ __launch_bounds__(256) void gemm_both(
    const float* __restrict__ phr, const float* __restrict__ W,
    const float* __restrict__ bias,
    const float* __restrict__ vis, const float* __restrict__ U,
    float* __restrict__ whY, us* __restrict__ uvYT,
    float* __restrict__ out_sgf)
{
    __shared__ __align__(16) us As[64 * 40];
    __shared__ __align__(16) us Bs[64 * 40];
    int blk = blockIdx.x;
    if (blk < 256) {
        int bx = blk % 32, by = blk / 32;
        gemm64(As, Bs, phr, W, bias, whY, nullptr, NQS, bx, by,
               by == 0 ? out_sgf : nullptr);
    } else {
        blk -= 256;
        int bx = blk % 64, by = blk / 64;
        gemm64(As, Bs, vis, U, bias, nullptr, uvYT, NFS, bx, by, nullptr);
    }
}

// ---------------- energize: in-thread n-reduction, zero shuffle-reduce ------
// block = (b, q-quad), 4 waves = n-quarters. lane owns v-pair (2*lane, 2*lane+1).
// Yq (fp32) and w are wave-uniform -> scalar loads; Yv from transposed uvYT.
__global__ __launch_bounds__(256) void energize(
    const float* __restrict__ whY,    // [2048][512] fp32 = exp(2(Wh+b))
    const us* __restrict__ uvYT,      // [32][512][128] bf16 = exp(2Uv), [n][v]
    const float* __restrict__ wvec,   // [512]
    float* __restrict__ out_w, float* __restrict__ out_e,
    us* __restrict__ p_bf, us* __restrict__ p_lo)   // [2048][128]
{
    const float LOG2E = 1.4426950408889634f;
    int blk = blockIdx.x;
    blk = (blk & 7) * 64 + (blk >> 3);    // bijective XCD swizzle (512 = 8*64)
    const int b    = blk >> 4;            // b-major: 16 blocks share uvYT[b]
    const int qq4  = blk & 15;
    const int tid  = threadIdx.x;
    const int wave = __builtin_amdgcn_readfirstlane(tid >> 6);  // n-quarter
    const int lane = tid & 63;
    const int q0   = qq4 * 4;

    __shared__ float part[4][4][NLV];     // [q][nq][v]

    // sumw (once per wave)
    float4 sw0 = *(const float4*)(wvec + lane * 8);
    float4 sw1 = *(const float4*)(wvec + lane * 8 + 4);
    float sumw = sw0.x + sw0.y + sw0.z + sw0.w + sw1.x + sw1.y + sw1.z + sw1.w;
    #pragma unroll
    for (int off = 32; off; off >>= 1) sumw += __shfl_xor(sumw, off);

    const float* yqp = whY + (size_t)(b * NLQ + q0) * NBN + wave * 128;
    const float* wp  = wvec + wave * 128;
    const us*    uvp = uvYT + ((size_t)b * NBN + wave * 128) * NLV + 2 * lane;

    float acc[4][2] = {};
    #pragma unroll 2
    for (int nc = 0; nc < 128; nc += 8) {
        unsigned int yv[8];
        #pragma unroll
        for (int k = 0; k < 8; ++k)
            yv[k] = *(const unsigned int*)(uvp + (size_t)(nc + k) * NLV);
        #pragma unroll
        for (int k = 0; k < 8; ++k) {
            float x0 = blo(yv[k]), x1 = bhi(yv[k]);
            float wk = wp[nc + k];                      // uniform -> SGPR
            #pragma unroll
            for (int q = 0; q < 4; ++q) {
                float yq = yqp[q * NBN + nc + k];       // uniform -> SGPR
                float d0 = fmaf(x0, yq, 1.f);
                float d1 = fmaf(x1, yq, 1.f);
                acc[q][0] = fmaf(wk, __builtin_amdgcn_rcpf(d0), acc[q][0]);
                acc[q][1] = fmaf(wk, __builtin_amdgcn_rcpf(d1), acc[q][1]);
            }
        }
    }
    #pragma unroll
    for (int q = 0; q < 4; ++q) {
        float2 t = { acc[q][0], acc[q][1] };
        *(float2*)&part[q][wave][2 * lane] = t;
    }
    __syncthreads();

    // softmax: wave w handles q = w (exactly 4 q, 4 waves)
    const int q = wave;
    float s0 = 0.f, s1 = 0.f;
    #pragma unroll
    for (int nq = 0; nq < 4; ++nq) {
        s0 += part[q][nq][2 * lane];
        s1 += part[q][nq][2 * lane + 1];
    }
    float e0 = sumw - 2.f * s0;
    float e1 = sumw - 2.f * s1;
    float m = fmaxf(e0, e1);
    #pragma unroll
    for (int off = 32; off; off >>= 1) m = fmaxf(m, __shfl_xor(m, off));
    float x0 = __builtin_amdgcn_exp2f((e0 - m) * LOG2E);
    float x1 = __builtin_amdgcn_exp2f((e1 - m) * LOG2E);
    float ss = x0 + x1;
    #pragma unroll
    for (int off = 32; off; off >>= 1) ss += __shfl_xor(ss, off);
    float inv = __builtin_amdgcn_rcpf(ss);
    float p0 = x0 * inv, p1 = x1 * inv;

    const size_t row = (size_t)(b * NLQ + q0 + q);
    float2 ep = { e0, e1 };
    float2 pp = { p0, p1 };
    *(float2*)(out_e + row * NLV + 2 * lane) = ep;
    *(float2*)(out_w + row * NLV + 2 * lane) = pp;
    // bf16 p + bf16 correction (restores fp32 accuracy in the MFMA)
    unsigned int pb0 = f2bf(p0), pb1 = f2bf(p1);
    float lo0 = p0 - __uint_as_float(pb0 << 16);
    float lo1 = p1 - __uint_as_float(pb1 << 16);
    unsigned int lb0 = f2bf(lo0), lb1 = f2bf(lo1);
    *(unsigned int*)(p_bf + row * NLV + 2 * lane) = pb0 | (pb1 << 16);
    *(unsigned int*)(p_lo + row * NLV + 2 * lane) = lb0 | (lb1 << 16);
}

// ---------------- aligned via MFMA: out = (P + P_lo) . V ---------------------
// block = (b, f-tile of 64). Stages its own V slice from fp32 vis:
// load coalesced, truncate to bf16, LDS-transpose to Vs[f][v] (pad 136).
// A-frags (P) gather directly from L2; B-frags from LDS.
__global__ __launch_bounds__(256) void aligned_mfma(
    const us* __restrict__ p_bf, const us* __restrict__ p_lo,  // [2048][128]
    const float* __restrict__ vis,                             // [32][128][1024]
    float* __restrict__ out_sgf)
{
    int blk = blockIdx.x;
    blk = (blk & 7) * 64 + (blk >> 3);    // XCD swizzle, b-major
    const int b    = blk >> 4;
    const int ft   = blk & 15;
    const int tid  = threadIdx.x;
    const int wave = tid >> 6;
    const int lane = tid & 63;
    const int wm   = (wave >> 1) * 32;    // q offset
    const int wf   = (wave & 1) * 32;     // f offset within the 64-tile
    const int fm   = lane & 15;
    const int fko  = (lane >> 4) * 8;

    __shared__ us Vs[64][136];            // [f][v], row stride 272 B (16B mult)

    {   // stage V: thread owns (v = tid>>1, f-half = (tid&1)*32)
        const int v  = tid >> 1;
        const int fh = (tid & 1) * 32;
        const float* vp = vis + ((size_t)b * NLV + v) * NFS + ft * 64 + fh;
        #pragma unroll
        for (int r = 0; r < 8; ++r) {
            float4 x = ((const float4*)vp)[r];
            Vs[fh + 4 * r + 0][v] = (us)(__float_as_uint(x.x) >> 16);
            Vs[fh + 4 * r + 1][v] = (us)(__float_as_uint(x.y) >> 16);
            Vs[fh + 4 * r + 2][v] = (us)(__float_as_uint(x.z) >> 16);
            Vs[fh + 4 * r + 3][v] = (us)(__float_as_uint(x.w) >> 16);
        }
    }
    __syncthreads();

    floatx4 acc[2][2] = {};
    const us* pA  = p_bf + ((size_t)b * NLQ + wm + fm) * NLV + fko;
    const us* pAl = p_lo + ((size_t)b * NLQ + wm + fm) * NLV + fko;

    #pragma unroll
    for (int ks = 0; ks < 4; ++ks) {
        bf16x8 a[2], al[2], bb2[2];
        #pragma unroll
        for (int i = 0; i < 2; ++i) {
            a[i]  = *(const bf16x8*)(pA  + (size_t)i * 16 * NLV + ks * 32);
            al[i] = *(const bf16x8*)(pAl + (size_t)i * 16 * NLV + ks * 32);
        }
        #pragma unroll
        for (int j = 0; j < 2; ++j)
            bb2[j] = *(const bf16x8*)&Vs[wf + 16 * j + fm][ks * 32 + fko];
        #pragma unroll
        for (int i = 0; i < 2; ++i)
            #pragma unroll
            for (int j = 0; j < 2; ++j) {
                acc[i][j] = __builtin_amdgcn_mfma_f32_16x16x32_bf16(a[i],  bb2[j], acc[i][j], 0, 0, 0);
                acc[i][j] = __builtin_amdgcn_mfma_f32_16x16x32_bf16(al[i], bb2[j], acc[i][j], 0, 0, 0);
            }
    }

    const int cr = (lane >> 4) * 4;
    const int cc = lane & 15;
    #pragma unroll
    for (int i = 0; i < 2; ++i)
        #pragma unroll
        for (int j = 0; j < 2; ++j)
            #pragma unroll
            for (int r = 0; r < 4; ++r) {
                int q = wm + 16 * i + cr + r;
                int f = ft * 64 + wf + 16 * j + cc;
                size_t row = (size_t)b * NLQ + q;
                out_sgf[row * (NQS + NFS) + NQS + f] = acc[i][j][r];
            }
}

extern "C" void kernel_launch(void* const* d_in, const int* in_sizes, int n_in,
                              void* d_out, int out_size, void* d_ws, size_t ws_size,
                              hipStream_t stream) {
    const float* phr  = (const float*)d_in[0];
    const float* vis  = (const float*)d_in[1];
    const float* W    = (const float*)d_in[2];
    const float* U    = (const float*)d_in[3];
    const float* bias = (const float*)d_in[4];
    const float* wvec = (const float*)d_in[5];

    char* ws = (char*)d_ws;
    float* whY  = (float*)ws;                     // 4 MB [2048][512] fp32
    us* uvYT    = (us*)(ws + (4u << 20));         // 4 MB [32][512][128] bf16
    us* p_bf    = (us*)(ws + (8u << 20));         // 512 KB [2048][128]
    us* p_lo    = (us*)(ws + (8u << 20) + (512u << 10));    // 512 KB

    float* out     = (float*)d_out;
    float* out_sgf = out;
    float* out_w   = out_sgf + (size_t)NB * NLQ * (NQS + NFS);
    float* out_e   = out_w   + (size_t)NB * NLQ * NLV;

    gemm_both<<<768, 256, 0, stream>>>(phr, W, bias, vis, U, whY, uvYT, out_sgf);
    energize<<<512, 256, 0, stream>>>(whY, uvYT, wvec, out_w, out_e, p_bf, p_lo);
    aligned_mfma<<<512, 256, 0, stream>>>(p_bf, p_lo, vis, out_sgf);
}

// Round 6
// 124.950 us; speedup vs baseline: 1.1044x; 1.0108x over previous
//
#include <hip/hip_runtime.h>

#define NB  32
#define NLQ 64
#define NLV 128
#define NQS 512
#define NFS 1024
#define NBN 512
#define CC  2.8853900817779268f   // 2*log2(e):  exp(2x) = exp2(CC*x)

typedef float  floatx4 __attribute__((ext_vector_type(4)));
typedef __bf16 bf16x8  __attribute__((ext_vector_type(8)));
typedef unsigned short us;

__device__ __forceinline__ us f2bf(float f) {
    unsigned int u = __float_as_uint(f);
    u += 0x7fffu + ((u >> 16) & 1u);   // round-to-nearest-even
    return (us)(u >> 16);
}
// truncating pack of two fp32 -> packed bf16x2, one v_perm_b32
__device__ __forceinline__ unsigned int pktrunc(float lo, float hi) {
    return __builtin_amdgcn_perm(__float_as_uint(hi), __float_as_uint(lo), 0x07060302u);
}
__device__ __forceinline__ float blo(unsigned int u) {
    return __uint_as_float(u << 16);
}
__device__ __forceinline__ float bhi(unsigned int u) {
    return __uint_as_float(u & 0xffff0000u);
}

// ---------------- GEMM: 64x64 tile, K-tile 32, fp32 in (cvt in-reg), 4 waves
// 768-block grid (~3 blocks/CU) -> inter-block overlap hides latency.
// mode Yq (whYp != null): C = exp2(CC*(acc+bias)) stored FP32 to whY[2048][512]
//   by==0 blocks also copy fp32 A rows into out_sgf[:, 0:512].
// mode Yv: C = exp2(CC*acc) stored bf16 TRANSPOSED to uvYT[b][n][v] via an
//   LDS transpose (reusing the staging buffer) so global stores are coalesced
//   (the direct scatter was ~8x write-amplified: 8B used per 64B sector).
__device__ __forceinline__ void gemm64(
    us* smem,                             // 2*64*40 us staging (As|Bs)
    const float* __restrict__ A, const float* __restrict__ Bt,
    const float* __restrict__ bias,
    float* __restrict__ whYp, us* __restrict__ uvYTp,
    int K, int bx, int by, float* __restrict__ sgf)
{
    us* As = smem;
    us* Bs = smem + 64 * 40;
    const int tid  = threadIdx.x;
    const int m0   = bx * 64;
    const int n0   = by * 64;
    const int wave = tid >> 6;
    const int lane = tid & 63;
    const int wm   = (wave >> 1) * 32;
    const int wn   = (wave & 1) * 32;
    const int srow = tid >> 2;          // 0..63
    const int sk   = (tid & 3) * 8;     // k offset (elements): 0,8,16,24
    const int fm   = lane & 15;
    const int fko  = (lane >> 4) * 8;

    floatx4 acc[2][2] = {};
    const float* ag = A  + (size_t)(m0 + srow) * K + sk;
    const float* bg = Bt + (size_t)(n0 + srow) * K + sk;

    float4 a0 = *(const float4*)(ag),     a1 = *(const float4*)(ag + 4);
    float4 b0 = *(const float4*)(bg),     b1 = *(const float4*)(bg + 4);

    for (int k0 = 0; k0 < K; k0 += 32) {
        __syncthreads();
        if (sgf) {          // concat left half: fp32, exact
            float* d = sgf + (size_t)(m0 + srow) * (NQS + NFS) + k0 + sk;
            *(float4*)d       = a0;
            *(float4*)(d + 4) = a1;
        }
        uint4 av = { pktrunc(a0.x, a0.y), pktrunc(a0.z, a0.w),
                     pktrunc(a1.x, a1.y), pktrunc(a1.z, a1.w) };
        uint4 bv = { pktrunc(b0.x, b0.y), pktrunc(b0.z, b0.w),
                     pktrunc(b1.x, b1.y), pktrunc(b1.z, b1.w) };
        *(uint4*)(As + srow * 40 + sk) = av;
        *(uint4*)(Bs + srow * 40 + sk) = bv;
        const int kn = k0 + 32;
        if (kn < K) {                   // next-tile prefetch; hidden by co-resident blocks
            a0 = *(const float4*)(ag + kn); a1 = *(const float4*)(ag + kn + 4);
            b0 = *(const float4*)(bg + kn); b1 = *(const float4*)(bg + kn + 4);
        }
        __syncthreads();
        bf16x8 am[2], bn[2];
        #pragma unroll
        for (int i = 0; i < 2; ++i)
            am[i] = *(const bf16x8*)(As + (wm + 16 * i + fm) * 40 + fko);
        #pragma unroll
        for (int j = 0; j < 2; ++j)
            bn[j] = *(const bf16x8*)(Bs + (wn + 16 * j + fm) * 40 + fko);
        #pragma unroll
        for (int i = 0; i < 2; ++i)
            #pragma unroll
            for (int j = 0; j < 2; ++j)
                acc[i][j] = __builtin_amdgcn_mfma_f32_16x16x32_bf16(am[i], bn[j], acc[i][j], 0, 0, 0);
    }

    // C/D layout: col = lane&15, row = (lane>>4)*4 + reg
    const int cr = (lane >> 4) * 4;
    const int cc = lane & 15;
    if (whYp) {
        #pragma unroll
        for (int j = 0; j < 2; ++j) {
            int gn = n0 + wn + 16 * j + cc;
            float bj = bias[gn];
            #pragma unroll
            for (int i = 0; i < 2; ++i)
                #pragma unroll
                for (int r = 0; r < 4; ++r) {
                    int gm = m0 + wm + 16 * i + cr + r;
                    whYp[(size_t)gm * NBN + gn] =
                        __builtin_amdgcn_exp2f(CC * (acc[i][j][r] + bj));
                }
        }
    } else {
        // ---- LDS transpose epilogue: Cs[n_local][v_local], stride 72 us ----
        us* Cs = smem;                     // 64*72 = 4608 us <= 5120 available
        __syncthreads();                   // all MFMA LDS reads done
        #pragma unroll
        for (int i = 0; i < 2; ++i)
            #pragma unroll
            for (int j = 0; j < 2; ++j) {
                int nl = wn + 16 * j + cc;
                int vl = wm + 16 * i + cr;
                #pragma unroll
                for (int r = 0; r < 4; ++r)
                    Cs[nl * 72 + vl + r] =
                        f2bf(__builtin_amdgcn_exp2f(CC * acc[i][j][r]));
            }
        __syncthreads();
        const int bb    = m0 >> 7;         // batch
        const int vbase = m0 & 127;        // 0 or 64
        const int nl    = tid >> 2;        // 0..63
        const int vc    = (tid & 3) * 16;  // 16-v chunk
        uint4 t0 = *(const uint4*)(Cs + nl * 72 + vc);
        uint4 t1 = *(const uint4*)(Cs + nl * 72 + vc + 8);
        us* dst = uvYTp + ((size_t)bb * NBN + n0 + nl) * NLV + vbase + vc;
        *(uint4*)dst       = t0;
        *(uint4*)(dst + 8) = t1;
    }
}

// blocks 0..255: Yq (M=2048,K=512, nbx=32); 256..767: Yv (M=4096,K=1024, nbx=64)
// bx = blk % nbx with 8|nbx -> blocks sharing A-rows land on one XCD's L2
__global__ __launch_bounds__(256) void gemm_both(
    const float* __restrict__ phr, const float* __restrict__ W,
    const float* __restrict__ bias,
    const float* __restrict__ vis, const float* __restrict__ U,
    float* __restrict__ whY, us* __restrict__ uvYT,
    float* __restrict__ out_sgf)
{
    __shared__ __align__(16) us smem[2 * 64 * 40];
    int blk = blockIdx.x;
    if (blk < 256) {
        int bx = blk % 32, by = blk / 32;
        gemm64(smem, phr, W, bias, whY, nullptr, NQS, bx, by,
               by == 0 ? out_sgf : nullptr);
    } else {
        blk -= 256;
        int bx = blk % 64, by = blk / 64;
        gemm64(smem, vis, U, bias, nullptr, uvYT, NFS, bx, by, nullptr);
    }
}

// ---------------- energize: in-thread n-reduction, paired rcp ---------------
// block = (b, q-quad), 512 threads, 8 waves = n-eighths (4 waves/SIMD for
// latency/trans hiding). lane owns v-pair. Paired-rcp halves trans-pipe:
//   w0/d0 + w1/d1 = (w0*d1 + w1*d0) / (d0*d1)   (d >= 1, overflow -> 0, safe)
__global__ __launch_bounds__(512) void energize(
    const float* __restrict__ whY,    // [2048][512] fp32 = exp(2(Wh+b))
    const us* __restrict__ uvYT,      // [32][512][128] bf16 = exp(2Uv), [n][v]
    const float* __restrict__ wvec,   // [512]
    float* __restrict__ out_w, float* __restrict__ out_e,
    us* __restrict__ p_bf, us* __restrict__ p_lo)   // [2048][128]
{
    const float LOG2E = 1.4426950408889634f;
    int blk = blockIdx.x;
    blk = (blk & 7) * 64 + (blk >> 3);    // bijective XCD swizzle (512 = 8*64)
    const int b    = blk >> 4;            // b-major: 16 blocks share uvYT[b]
    const int qq4  = blk & 15;
    const int tid  = threadIdx.x;
    const int wave = __builtin_amdgcn_readfirstlane(tid >> 6);  // n-eighth 0..7
    const int lane = tid & 63;
    const int q0   = qq4 * 4;

    __shared__ float part[4][8][NLV];     // [q][n-eighth][v] = 16 KB

    // sumw (once per wave)
    float4 sw0 = *(const float4*)(wvec + lane * 8);
    float4 sw1 = *(const float4*)(wvec + lane * 8 + 4);
    float sumw = sw0.x + sw0.y + sw0.z + sw0.w + sw1.x + sw1.y + sw1.z + sw1.w;
    #pragma unroll
    for (int off = 32; off; off >>= 1) sumw += __shfl_xor(sumw, off);

    const float* yqp = whY + (size_t)(b * NLQ + q0) * NBN + wave * 64;
    const float* wp  = wvec + wave * 64;
    const us*    uvp = uvYT + ((size_t)b * NBN + wave * 64) * NLV + 2 * lane;

    float acc[4][2] = {};
    #pragma unroll 2
    for (int nc = 0; nc < 64; nc += 8) {
        unsigned int yv[8];
        #pragma unroll
        for (int k = 0; k < 8; ++k)
            yv[k] = *(const unsigned int*)(uvp + (size_t)(nc + k) * NLV);
        #pragma unroll
        for (int kk = 0; kk < 4; ++kk) {
            const int k0 = nc + 2 * kk, k1 = k0 + 1;
            float x0a = blo(yv[2 * kk]),     x0b = bhi(yv[2 * kk]);     // n=k0
            float x1a = blo(yv[2 * kk + 1]), x1b = bhi(yv[2 * kk + 1]); // n=k1
            float w0 = wp[k0], w1 = wp[k1];                 // uniform -> SGPR
            #pragma unroll
            for (int q = 0; q < 4; ++q) {
                float y0 = yqp[q * NBN + k0];               // uniform -> SGPR
                float y1 = yqp[q * NBN + k1];
                float d0a = fmaf(x0a, y0, 1.f), d1a = fmaf(x1a, y1, 1.f);
                float d0b = fmaf(x0b, y0, 1.f), d1b = fmaf(x1b, y1, 1.f);
                float numa = fmaf(w0, d1a, w1 * d0a);
                float numb = fmaf(w0, d1b, w1 * d0b);
                acc[q][0] = fmaf(numa, __builtin_amdgcn_rcpf(d0a * d1a), acc[q][0]);
                acc[q][1] = fmaf(numb, __builtin_amdgcn_rcpf(d0b * d1b), acc[q][1]);
            }
        }
    }
    #pragma unroll
    for (int q = 0; q < 4; ++q) {
        float2 t = { acc[q][0], acc[q][1] };
        *(float2*)&part[q][wave][2 * lane] = t;
    }
    __syncthreads();

    // softmax: wave w handles q = w (4 q on waves 0..3)
    if (wave < 4) {
        const int q = wave;
        float s0 = 0.f, s1 = 0.f;
        #pragma unroll
        for (int nq = 0; nq < 8; ++nq) {
            s0 += part[q][nq][2 * lane];
            s1 += part[q][nq][2 * lane + 1];
        }
        float e0 = sumw - 2.f * s0;
        float e1 = sumw - 2.f * s1;
        float m = fmaxf(e0, e1);
        #pragma unroll
        for (int off = 32; off; off >>= 1) m = fmaxf(m, __shfl_xor(m, off));
        float x0 = __builtin_amdgcn_exp2f((e0 - m) * LOG2E);
        float x1 = __builtin_amdgcn_exp2f((e1 - m) * LOG2E);
        float ss = x0 + x1;
        #pragma unroll
        for (int off = 32; off; off >>= 1) ss += __shfl_xor(ss, off);
        float inv = __builtin_amdgcn_rcpf(ss);
        float p0 = x0 * inv, p1 = x1 * inv;

        const size_t row = (size_t)(b * NLQ + q0 + q);
        float2 ep = { e0, e1 };
        float2 pp = { p0, p1 };
        *(float2*)(out_e + row * NLV + 2 * lane) = ep;
        *(float2*)(out_w + row * NLV + 2 * lane) = pp;
        // bf16 p + bf16 correction (restores fp32 accuracy in the MFMA)
        unsigned int pb0 = f2bf(p0), pb1 = f2bf(p1);
        float lo0 = p0 - __uint_as_float(pb0 << 16);
        float lo1 = p1 - __uint_as_float(pb1 << 16);
        unsigned int lb0 = f2bf(lo0), lb1 = f2bf(lo1);
        *(unsigned int*)(p_bf + row * NLV + 2 * lane) = pb0 | (pb1 << 16);
        *(unsigned int*)(p_lo + row * NLV + 2 * lane) = lb0 | (lb1 << 16);
    }
}

// ---------------- aligned via MFMA: out = (P + P_lo) . V ---------------------
// block = (b, f-tile of 64). Stages its own V slice from fp32 vis:
// load coalesced, truncate to bf16, LDS-transpose to Vs[f][v] (pad 136).
// A-frags (P) gather directly from L2; B-frags from LDS.
__global__ __launch_bounds__(256) void aligned_mfma(
    const us* __restrict__ p_bf, const us* __restrict__ p_lo,  // [2048][128]
    const float* __restrict__ vis,                             // [32][128][1024]
    float* __restrict__ out_sgf)
{
    int blk = blockIdx.x;
    blk = (blk & 7) * 64 + (blk >> 3);    // XCD swizzle, b-major
    const int b    = blk >> 4;
    const int ft   = blk & 15;
    const int tid  = threadIdx.x;
    const int wave = tid >> 6;
    const int lane = tid & 63;
    const int wm   = (wave >> 1) * 32;    // q offset
    const int wf   = (wave & 1) * 32;     // f offset within the 64-tile
    const int fm   = lane & 15;
    const int fko  = (lane >> 4) * 8;

    __shared__ us Vs[64][136];            // [f][v], row stride 272 B (16B mult)

    {   // stage V: thread owns (v = tid>>1, f-half = (tid&1)*32)
        const int v  = tid >> 1;
        const int fh = (tid & 1) * 32;
        const float* vp = vis + ((size_t)b * NLV + v) * NFS + ft * 64 + fh;
        #pragma unroll
        for (int r = 0; r < 8; ++r) {
            float4 x = ((const float4*)vp)[r];
            Vs[fh + 4 * r + 0][v] = (us)(__float_as_uint(x.x) >> 16);
            Vs[fh + 4 * r + 1][v] = (us)(__float_as_uint(x.y) >> 16);
            Vs[fh + 4 * r + 2][v] = (us)(__float_as_uint(x.z) >> 16);
            Vs[fh + 4 * r + 3][v] = (us)(__float_as_uint(x.w) >> 16);
        }
    }
    __syncthreads();

    floatx4 acc[2][2] = {};
    const us* pA  = p_bf + ((size_t)b * NLQ + wm + fm) * NLV + fko;
    const us* pAl = p_lo + ((size_t)b * NLQ + wm + fm) * NLV + fko;

    #pragma unroll
    for (int ks = 0; ks < 4; ++ks) {
        bf16x8 a[2], al[2], bb2[2];
        #pragma unroll
        for (int i = 0; i < 2; ++i) {
            a[i]  = *(const bf16x8*)(pA  + (size_t)i * 16 * NLV + ks * 32);
            al[i] = *(const bf16x8*)(pAl + (size_t)i * 16 * NLV + ks * 32);
        }
        #pragma unroll
        for (int j = 0; j < 2; ++j)
            bb2[j] = *(const bf16x8*)&Vs[wf + 16 * j + fm][ks * 32 + fko];
        #pragma unroll
        for (int i = 0; i < 2; ++i)
            #pragma unroll
            for (int j = 0; j < 2; ++j) {
                acc[i][j] = __builtin_amdgcn_mfma_f32_16x16x32_bf16(a[i],  bb2[j], acc[i][j], 0, 0, 0);
                acc[i][j] = __builtin_amdgcn_mfma_f32_16x16x32_bf16(al[i], bb2[j], acc[i][j], 0, 0, 0);
            }
    }

    const int cr = (lane >> 4) * 4;
    const int cc = lane & 15;
    #pragma unroll
    for (int i = 0; i < 2; ++i)
        #pragma unroll
        for (int j = 0; j < 2; ++j)
            #pragma unroll
            for (int r = 0; r < 4; ++r) {
                int q = wm + 16 * i + cr + r;
                int f = ft * 64 + wf + 16 * j + cc;
                size_t row = (size_t)b * NLQ + q;
                out_sgf[row * (NQS + NFS) + NQS + f] = acc[i][j][r];
            }
}

extern "C" void kernel_launch(void* const* d_in, const int* in_sizes, int n_in,
                              void* d_out, int out_size, void* d_ws, size_t ws_size,
                              hipStream_t stream) {
    const float* phr  = (const float*)d_in[0];
    const float* vis  = (const float*)d_in[1];
    const float* W    = (const float*)d_in[2];
    const float* U    = (const float*)d_in[3];
    const float* bias = (const float*)d_in[4];
    const float* wvec = (const float*)d_in[5];

    char* ws = (char*)d_ws;
    float* whY  = (float*)ws;                     // 4 MB [2048][512] fp32
    us* uvYT    = (us*)(ws + (4u << 20));         // 4 MB [32][512][128] bf16
    us* p_bf    = (us*)(ws + (8u << 20));         // 512 KB [2048][128]
    us* p_lo    = (us*)(ws + (8u << 20) + (512u << 10));    // 512 KB

    float* out     = (float*)d_out;
    float* out_sgf = out;
    float* out_w   = out_sgf + (size_t)NB * NLQ * (NQS + NFS);
    float* out_e   = out_w   + (size_t)NB * NLQ * NLV;

    gemm_both<<<768, 256, 0, stream>>>(phr, W, bias, vis, U, whY, uvYT, out_sgf);
    energize<<<512, 512, 0, stream>>>(whY, uvYT, wvec, out_w, out_e, p_bf, p_lo);
    aligned_mfma<<<512, 256, 0, stream>>>(p_bf, p_lo, vis, out_sgf);
}